// Round 9
// baseline (256.435 us; speedup 1.0000x reference)
//
#include <hip/hip_runtime.h>
#include <hip/hip_bf16.h>
#include <math.h>

#define ENC2 1024
#define DECD 1024
#define ATT 512
#define NBATCH 32
#define SEQ 2048
#define MTOT (NBATCH*SEQ)

#define BM 128
#define BN2 256
#define BK 64    // two 32-k halves per K-tile

typedef __attribute__((ext_vector_type(8))) short short8;
typedef __attribute__((ext_vector_type(4))) short short4v;
typedef __attribute__((ext_vector_type(4))) float f32x4;

static __device__ __forceinline__ unsigned pk2(float a, float b) {
  __hip_bfloat162 h = __float22bfloat162_rn(float2{a, b});  // v_cvt_pk_bf16_f32
  union { __hip_bfloat162 h; unsigned u; } c; c.h = h;
  return c.u;
}

static __device__ __forceinline__ float fast_tanh(float x) {
  float ax = fabsf(x);
  float e = __expf(2.f * ax);
  float t = 1.f - 2.f / (e + 1.f);
  return copysignf(t, x);
}

static __device__ __forceinline__ void gload_lds16(const void* g, void* l) {
  __builtin_amdgcn_global_load_lds(
      (const __attribute__((address_space(1))) void*)g,
      (__attribute__((address_space(3))) void*)l, 16, 0, 0);
}

// ---- fused prep (R7, unchanged): blocks 0..127 U_w -> U_wT bf16; 128..255 Wsb ----
__global__ __launch_bounds__(512) void prep_kernel(
    const float* __restrict__ U_w, short* __restrict__ U_wT,
    const float* __restrict__ dh, const float* __restrict__ W_w,
    const float* __restrict__ W_b, const float* __restrict__ U_b,
    float* __restrict__ Wsb) {
  __shared__ float tile[64][65];
  __shared__ float dsh[DECD];
  __shared__ float part[4][128];
  const int t = threadIdx.x;

  if (blockIdx.x < 128) {
    const int kt = blockIdx.x >> 3;
    const int ct = blockIdx.x & 7;
    const int k0 = kt * 64, c0 = ct * 64;
    const int r = t >> 3, cc = (t & 7) * 8;
    float4 v0 = *(const float4*)(U_w + (size_t)(k0 + r) * ATT + c0 + cc);
    float4 v1 = *(const float4*)(U_w + (size_t)(k0 + r) * ATT + c0 + cc + 4);
    tile[r][cc+0] = v0.x; tile[r][cc+1] = v0.y; tile[r][cc+2] = v0.z; tile[r][cc+3] = v0.w;
    tile[r][cc+4] = v1.x; tile[r][cc+5] = v1.y; tile[r][cc+6] = v1.z; tile[r][cc+7] = v1.w;
    __syncthreads();
    const int c = t >> 3, kk = (t & 7) * 8;
    union { short8 s; unsigned u[4]; } o;
    o.u[0] = pk2(tile[kk+0][c], tile[kk+1][c]);
    o.u[1] = pk2(tile[kk+2][c], tile[kk+3][c]);
    o.u[2] = pk2(tile[kk+4][c], tile[kk+5][c]);
    o.u[3] = pk2(tile[kk+6][c], tile[kk+7][c]);
    *(short8*)(U_wT + (size_t)(c0 + c) * ENC2 + k0 + kk) = o.s;
  } else {
    const int bid = blockIdx.x - 128;
    const int b  = bid >> 2;
    const int a0 = (bid & 3) * 128;
    for (int i = t; i < DECD; i += 512) dsh[i] = dh[(size_t)b * DECD + i];
    __syncthreads();
    const int ks = t >> 7;
    const int a  = t & 127;
    const float* wp = W_w + (size_t)(ks * 256) * ATT + a0 + a;
    float s0 = 0.f, s1 = 0.f, s2 = 0.f, s3 = 0.f;
    #pragma unroll 4
    for (int kk = 0; kk < 256; kk += 4) {
      s0 = fmaf(dsh[ks*256 + kk + 0], wp[(size_t)(kk + 0) * ATT], s0);
      s1 = fmaf(dsh[ks*256 + kk + 1], wp[(size_t)(kk + 1) * ATT], s1);
      s2 = fmaf(dsh[ks*256 + kk + 2], wp[(size_t)(kk + 2) * ATT], s2);
      s3 = fmaf(dsh[ks*256 + kk + 3], wp[(size_t)(kk + 3) * ATT], s3);
    }
    part[ks][a] = (s0 + s1) + (s2 + s3);
    __syncthreads();
    if (t < 128) {
      float v = part[0][t] + part[1][t] + part[2][t] + part[3][t];
      Wsb[(size_t)b * ATT + a0 + t] = v + W_b[a0 + t] + U_b[a0 + t];
    }
  }
}

// ---- main GEMM+tanh+vdot: 8-phase-style schedule (T3+T4+T5) ----
// LDS per half-tile (R5's verified conflict-free subtiled layouts):
//   A f32 : [m_sub(8)][sel(2)][kh(4)][fr(16)][4]  = 16 KB
//   B bf16: [n_sub(16)][kh(4)][fr(16)][8]         = 16 KB
// Buffers: As[2buf][2half], Bs[2buf][2half] -> 128 KB, 1 block/CU.
// Per phase: stage 1 half-tile group (4 gload_lds) || 12 ds_read + 16 cvt_pk
// || 16 MFMA; s_waitcnt vmcnt(8) (never 0 mid-loop); raw s_barrier.

#define STAGE(BUF, H, CB)                                                      \
  do {                                                                         \
    gload_lds16(aS + (CB),          &As[BUF][H][w*512]);                       \
    gload_lds16(aS + (CB) + 4,      &As[BUF][H][w*512 + 256]);                 \
    gload_lds16(bS0 + (CB),         &Bs[BUF][H][w*1024]);                      \
    gload_lds16(bS1 + (CB),         &Bs[BUF][H][w*1024 + 512]);                \
  } while (0)

#define COMPUTE(C, H)                                                          \
  do {                                                                         \
    short8 bf0 = *(const short8*)(&Bs[C][H][bB + 0*512]);                      \
    short8 bf1 = *(const short8*)(&Bs[C][H][bB + 1*512]);                      \
    short8 bf2 = *(const short8*)(&Bs[C][H][bB + 2*512]);                      \
    short8 bf3 = *(const short8*)(&Bs[C][H][bB + 3*512]);                      \
    __builtin_amdgcn_s_setprio(1);                                             \
    _Pragma("unroll")                                                          \
    for (int m = 0; m < 4; m++) {                                              \
      const float* ap = &As[C][H][aB + m*512];                                 \
      float4 x0 = *(const float4*)ap;                                          \
      float4 x1 = *(const float4*)(ap + 256);                                  \
      union { short8 s; unsigned u[4]; } aw;                                   \
      aw.u[0] = pk2(x0.x, x0.y); aw.u[1] = pk2(x0.z, x0.w);                    \
      aw.u[2] = pk2(x1.x, x1.y); aw.u[3] = pk2(x1.z, x1.w);                    \
      acc[m][0] = __builtin_amdgcn_mfma_f32_16x16x32_bf16(aw.s, bf0, acc[m][0], 0, 0, 0); \
      acc[m][1] = __builtin_amdgcn_mfma_f32_16x16x32_bf16(aw.s, bf1, acc[m][1], 0, 0, 0); \
      acc[m][2] = __builtin_amdgcn_mfma_f32_16x16x32_bf16(aw.s, bf2, acc[m][2], 0, 0, 0); \
      acc[m][3] = __builtin_amdgcn_mfma_f32_16x16x32_bf16(aw.s, bf3, acc[m][3], 0, 0, 0); \
    }                                                                          \
    __builtin_amdgcn_s_setprio(0);                                             \
  } while (0)

#define FENCE(VM)                                                              \
  asm volatile("s_waitcnt vmcnt(" VM ")" ::: "memory");                        \
  __builtin_amdgcn_s_barrier();

__global__ __launch_bounds__(512) void energy_kernel(
    const float* __restrict__ A,      // encoder [MTOT][ENC2] f32
    const short* __restrict__ Bt,     // U_wT [ATT][ENC2] bf16
    const float* __restrict__ Wsb,    // [NBATCH][ATT]
    const float* __restrict__ vw,     // [ATT]
    float* __restrict__ epart)        // [2][MTOT]
{
  __shared__ __align__(16) float As[2][2][4096];   // 64 KB
  __shared__ __align__(16) short Bs[2][2][8192];   // 64 KB -> 128 KB total

  const int tid = threadIdx.x;
  const int bid = blockIdx.x;
  const int mt = (bid >> 4) * 8 + (bid & 7);   // XCD pairing (same as R7)
  const int nt = (bid >> 3) & 1;
  const int row0 = mt * BM;
  const int col0 = nt * BN2;
  const int bidx = row0 / SEQ;

  const int lane = tid & 63;
  const int w    = tid >> 6;
  const int wm   = w >> 2;     // 0..1
  const int wn   = w & 3;      // 0..3
  const int fr   = lane & 15;
  const int kh   = lane >> 4;

  // fragment read bases (element units)
  const int aB = wm*2048 + kh*64 + fr*4;    // f32; + m*512 (+256 for sel=1)
  const int bB = wn*2048 + kh*128 + fr*8;   // bf16; + n*512

  // staging source pointers (per-lane, matching linear LDS slots; R5-verified)
  const float* aS  = A  + (size_t)(row0 + w*16 + (lane & 15)) * ENC2 + (lane >> 4) * 8;
  const short* bS0 = Bt + (size_t)(col0 + (2*w + 0)*16 + (lane & 15)) * ENC2 + (lane >> 4) * 8;
  const short* bS1 = Bt + (size_t)(col0 + (2*w + 1)*16 + (lane & 15)) * ENC2 + (lane >> 4) * 8;

  f32x4 acc[4][4];
  #pragma unroll
  for (int m = 0; m < 4; m++)
    #pragma unroll
    for (int n = 0; n < 4; n++) acc[m][n] = (f32x4){0.f, 0.f, 0.f, 0.f};

  // prologue: 3 half-tile groups in flight; vmcnt(8) -> tile0.h0 landed
  STAGE(0, 0, 0);
  STAGE(0, 1, 32);
  STAGE(1, 0, 64);
  FENCE("8");

  // steady state: 2 phases per K-tile; queue depth 12 ops; vmcnt(8) forces
  // exactly the half-tile needed by the NEXT phase (FIFO-verified).
  for (int t = 0; t < 14; t++) {
    const int c = t & 1;
    // PH_A: reads cur.h0; stages (t+1).h1 into other buf
    STAGE(c ^ 1, 1, (t + 1) * 64 + 32);
    COMPUTE(c, 0);
    FENCE("8");
    // PH_B: reads cur.h1; stages (t+2).h0 into cur buf (freed by PH_A barrier)
    STAGE(c, 0, (t + 2) * 64);
    COMPUTE(c, 1);
    FENCE("8");
  }
  // t = 14 (cur = buf0)
  STAGE(1, 1, 15 * 64 + 32);
  COMPUTE(0, 0);
  FENCE("8");
  COMPUTE(0, 1);          // no stage; queue = [(15).h0,(15).h1] = 8
  FENCE("4");             // force (15).h0
  // t = 15 (cur = buf1)
  COMPUTE(1, 0);
  FENCE("0");             // force (15).h1
  COMPUTE(1, 1);

  // epilogue: tanh + v-dot; lane-reduce over cols, cross-wn reduce via LDS
  float* eps = (float*)&As[0][0][0];   // buf0 free (last phases read buf1)
  float vv[4], wsb[4];
  #pragma unroll
  for (int n = 0; n < 4; n++) {
    const int gc = col0 + wn*64 + n*16 + fr;
    vv[n]  = vw[gc];
    wsb[n] = Wsb[(size_t)bidx * ATT + gc];
  }
  const int rg = lane >> 4;
  #pragma unroll
  for (int m = 0; m < 4; m++) {
    float part[4] = {0.f, 0.f, 0.f, 0.f};
    #pragma unroll
    for (int n = 0; n < 4; n++) {
      #pragma unroll
      for (int r = 0; r < 4; r++)
        part[r] += vv[n] * fast_tanh(acc[m][n][r] + wsb[n]);
    }
    #pragma unroll
    for (int r = 0; r < 4; r++) {
      float p = part[r];
      p += __shfl_xor(p, 1);
      p += __shfl_xor(p, 2);
      p += __shfl_xor(p, 4);
      p += __shfl_xor(p, 8);
      if (fr == 0) eps[wn*BM + wm*64 + m*16 + rg*4 + r] = p;
    }
  }
  __syncthreads();
  if (tid < BM) {
    float s = eps[0*BM + tid] + eps[1*BM + tid] + eps[2*BM + tid] + eps[3*BM + tid];
    epart[(size_t)nt * MTOT + row0 + tid] = s;
  }
}

// ---- softmax over S=2048 per batch row (sums the 2 partials), 512 thr ----
__global__ __launch_bounds__(512) void softmax_kernel(const float* __restrict__ epart,
                                                      float* __restrict__ out) {
  __shared__ float redmax[8];
  __shared__ float redsum[8];
  const int b = blockIdx.x, t = threadIdx.x;
  const float* e0 = epart + (size_t)b * SEQ;
  const float* e1 = epart + (size_t)MTOT + (size_t)b * SEQ;
  float vals[4];
  float mx = -1e30f;
  #pragma unroll
  for (int i = 0; i < 4; i++) {
    vals[i] = e0[t + i*512] + e1[t + i*512];
    mx = fmaxf(mx, vals[i]);
  }
  #pragma unroll
  for (int off = 1; off < 64; off <<= 1) mx = fmaxf(mx, __shfl_xor(mx, off));
  if ((t & 63) == 0) redmax[t >> 6] = mx;
  __syncthreads();
  mx = redmax[0];
  #pragma unroll
  for (int i = 1; i < 8; i++) mx = fmaxf(mx, redmax[i]);
  float sum = 0.f;
  #pragma unroll
  for (int i = 0; i < 4; i++) { vals[i] = expf(vals[i] - mx); sum += vals[i]; }
  #pragma unroll
  for (int off = 1; off < 64; off <<= 1) sum += __shfl_xor(sum, off);
  if ((t & 63) == 0) redsum[t >> 6] = sum;
  __syncthreads();
  float tot = 0.f;
  #pragma unroll
  for (int i = 0; i < 8; i++) tot += redsum[i];
  const float inv = 1.f / tot;
  #pragma unroll
  for (int i = 0; i < 4; i++) out[(size_t)b * SEQ + t + i*512] = vals[i] * inv;
}

extern "C" void kernel_launch(void* const* d_in, const int* in_sizes, int n_in,
                              void* d_out, int out_size, void* d_ws, size_t ws_size,
                              hipStream_t stream) {
  const float* dh  = (const float*)d_in[0];
  const float* enc = (const float*)d_in[1];
  const float* W_w = (const float*)d_in[2];
  const float* W_b = (const float*)d_in[3];
  const float* U_w = (const float*)d_in[4];
  const float* U_b = (const float*)d_in[5];
  const float* v_w = (const float*)d_in[6];
  float* out = (float*)d_out;

  char* ws = (char*)d_ws;
  float* epart = (float*)ws;                      // 512 KB
  float* Wsb   = (float*)(ws + 512 * 1024);       // 64 KB
  short* U_wT  = (short*)(ws + 576 * 1024);       // 1 MB

  prep_kernel<<<256, 512, 0, stream>>>(U_w, U_wT, dh, W_w, W_b, U_b, Wsb);
  energy_kernel<<<1024, 512, 0, stream>>>(enc, U_wT, Wsb, v_w, epart);
  softmax_kernel<<<NBATCH, 512, 0, stream>>>(epart, out);
}